// Round 1
// baseline (860.316 us; speedup 1.0000x reference)
//
#include <hip/hip_runtime.h>

#define H 2048
#define W 2048
#define KS 97     // int(2*(4*12+0.5)) = 97, odd
#define KH 48
#define TROWS 32  // output rows per thread in vertical pass

// ---------------------------------------------------------------------------
// Kernel 0: compute normalized Gaussian taps for both channels + alphas.
// wts layout: [0..96]=g0 (sigma0), [97..193]=g1 (sigma1), [194]=alpha0, [195]=alpha1
// ---------------------------------------------------------------------------
__global__ __launch_bounds__(128) void make_weights_k(const float* __restrict__ log_sigma,
                                                      const float* __restrict__ log_alpha,
                                                      float* __restrict__ wts) {
    __shared__ float e0s[KS], e1s[KS];
    __shared__ float sums[2];
    const int t = threadIdx.x;
    const float s0 = expf(log_sigma[0]);
    const float s1 = expf(log_sigma[1]);
    if (t < KS) {
        const float xx = (float)(t - KH);
        e0s[t] = expf(-(xx * xx) / (2.f * s0 * s0));
        e1s[t] = expf(-(xx * xx) / (2.f * s1 * s1));
    }
    __syncthreads();
    if (t == 0) {
        float a = 0.f, b = 0.f;
        for (int k = 0; k < KS; ++k) { a += e0s[k]; b += e1s[k]; }
        sums[0] = a; sums[1] = b;
    }
    __syncthreads();
    if (t < KS) {
        wts[t]      = e0s[t] / sums[0];
        wts[KS + t] = e1s[t] / sums[1];
    }
    if (t == 0) {
        wts[2 * KS]     = expf(log_alpha[0]);
        wts[2 * KS + 1] = expf(log_alpha[1]);
    }
}

// ---------------------------------------------------------------------------
// Kernel 1: vertical 97-tap blur of (d_rand*2-1), zero-padded SAME.
// Each thread owns one column and TROWS consecutive output rows; streams
// TROWS+96 input rows once, accumulating into registers. Gaussian taps live
// in a zero-padded LDS array so the inner accumulate is branchless.
// ---------------------------------------------------------------------------
__global__ __launch_bounds__(256) void vblur_k(const float* __restrict__ drand,
                                               const float* __restrict__ wts,
                                               float* __restrict__ tmp) {
    const int c = blockIdx.z;
    // padded taps: index k+TROWS-1 valid for k in [-(TROWS-1), KS+? ], zeros outside [0,KS)
    __shared__ float gsPad[TROWS - 1 + KS + TROWS];  // 160
    {
        const int tid = threadIdx.x;
        if (tid < TROWS - 1 + KS + TROWS) {
            float v = 0.f;
            const int k = tid - (TROWS - 1);
            if (k >= 0 && k < KS) v = wts[c * KS + k];
            gsPad[tid] = v;
        }
    }
    __syncthreads();

    const int j  = blockIdx.x * 256 + threadIdx.x;
    const int i0 = blockIdx.y * TROWS;
    const float* __restrict__ src = drand + (size_t)c * H * W;

    float acc[TROWS];
#pragma unroll
    for (int t = 0; t < TROWS; ++t) acc[t] = 0.f;

#pragma unroll
    for (int r = 0; r < TROWS + KS - 1; ++r) {   // 128 input rows
        const int row = i0 - KH + r;
        float v = 0.f;
        if (row >= 0 && row < H) v = __builtin_fmaf(src[(size_t)row * W + j], 2.f, -1.f);
#pragma unroll
        for (int t = 0; t < TROWS; ++t) {
            // tap index k = r - t; gsPad is zero where k outside [0,KS)
            acc[t] = __builtin_fmaf(gsPad[r - t + (TROWS - 1)], v, acc[t]);
        }
    }

    float* __restrict__ dst = tmp + (size_t)c * H * W;
#pragma unroll
    for (int t = 0; t < TROWS; ++t) dst[(size_t)(i0 + t) * W + j] = acc[t];
}

// ---------------------------------------------------------------------------
// Kernel 2: horizontal 97-tap blur (zero-padded SAME) of tmp -> (dy,dx),
// scale by alpha, build sample coords, bilinear-gather image(3ch)+mask(1ch).
// NOTE reference quirk: x-coordinate += dy (channel 0), y-coordinate += dx.
// ---------------------------------------------------------------------------
__global__ __launch_bounds__(256) void hblur_sample_k(const float* __restrict__ tmp,
                                                      const float* __restrict__ wts,
                                                      const float* __restrict__ image,
                                                      const float* __restrict__ mask,
                                                      float* __restrict__ out) {
    const int i   = blockIdx.y;
    const int j0  = blockIdx.x * 256;
    const int tid = threadIdx.x;

    __shared__ float s0[256 + KS - 1];
    __shared__ float s1[256 + KS - 1];
    __shared__ float g0s[KS], g1s[KS];

    if (tid < KS) { g0s[tid] = wts[tid]; g1s[tid] = wts[KS + tid]; }

    const float* __restrict__ t0 = tmp + (size_t)i * W;
    const float* __restrict__ t1 = tmp + (size_t)H * W + (size_t)i * W;
    for (int idx = tid; idx < 256 + KS - 1; idx += 256) {
        const int col = j0 - KH + idx;
        const bool ok = (col >= 0) && (col < W);
        s0[idx] = ok ? t0[col] : 0.f;
        s1[idx] = ok ? t1[col] : 0.f;
    }
    __syncthreads();

    const float alpha0 = wts[2 * KS];
    const float alpha1 = wts[2 * KS + 1];
    const int j = j0 + tid;

    float dy = 0.f, dx = 0.f;
#pragma unroll
    for (int k = 0; k < KS; ++k) {
        dy = __builtin_fmaf(g0s[k], s0[tid + k], dy);
        dx = __builtin_fmaf(g1s[k], s1[tid + k], dx);
    }
    dy *= alpha0;
    dx *= alpha1;

    const float step = 2.f / 2047.f;
    float xn = -1.f + (float)j * step + dy;   // gx + dy  (reference quirk)
    float yn = -1.f + (float)i * step + dx;   // gy + dx
    xn = fminf(fmaxf(xn, -1.f), 1.f);
    yn = fminf(fmaxf(yn, -1.f), 1.f);

    const float x = (xn + 1.f) * 0.5f * (float)(W - 1);
    const float y = (yn + 1.f) * 0.5f * (float)(H - 1);
    const float x0f = floorf(x), y0f = floorf(y);
    const float wx = x - x0f, wy = y - y0f;

    int x0 = (int)x0f, y0 = (int)y0f;
    int x1 = x0 + 1, y1 = y0 + 1;
    x0 = min(max(x0, 0), W - 1); x1 = min(max(x1, 0), W - 1);
    y0 = min(max(y0, 0), H - 1); y1 = min(max(y1, 0), H - 1);

    const float w00 = (1.f - wx) * (1.f - wy);
    const float w10 = wx * (1.f - wy);
    const float w01 = (1.f - wx) * wy;
    const float w11 = wx * wy;

    const size_t i00 = (size_t)y0 * W + x0;
    const size_t i10 = (size_t)y0 * W + x1;
    const size_t i01 = (size_t)y1 * W + x0;
    const size_t i11 = (size_t)y1 * W + x1;
    const size_t o   = (size_t)i * W + j;

#pragma unroll
    for (int c = 0; c < 3; ++c) {
        const float* __restrict__ p = image + (size_t)c * H * W;
        out[(size_t)c * H * W + o] =
            p[i00] * w00 + p[i10] * w10 + p[i01] * w01 + p[i11] * w11;
    }
    out[(size_t)3 * H * W + o] =
        mask[i00] * w00 + mask[i10] * w10 + mask[i01] * w01 + mask[i11] * w11;
}

// ---------------------------------------------------------------------------
extern "C" void kernel_launch(void* const* d_in, const int* in_sizes, int n_in,
                              void* d_out, int out_size, void* d_ws, size_t ws_size,
                              hipStream_t stream) {
    const float* image     = (const float*)d_in[0];  // (3,2048,2048)
    const float* mask      = (const float*)d_in[1];  // (1,2048,2048)
    const float* drand     = (const float*)d_in[2];  // (1,2,2048,2048)
    const float* log_sigma = (const float*)d_in[3];  // (2,)
    const float* log_alpha = (const float*)d_in[4];  // (2,)
    float* out = (float*)d_out;                      // 3*HW img ++ 1*HW mask

    float* tmp = (float*)d_ws;                       // 2*H*W floats (32 MB)
    float* wts = tmp + (size_t)2 * H * W;            // 196 floats

    make_weights_k<<<1, 128, 0, stream>>>(log_sigma, log_alpha, wts);
    vblur_k<<<dim3(W / 256, H / TROWS, 2), 256, 0, stream>>>(drand, wts, tmp);
    hblur_sample_k<<<dim3(W / 256, H), 256, 0, stream>>>(tmp, wts, image, mask, out);
}

// Round 2
// 348.179 us; speedup vs baseline: 2.4709x; 2.4709x over previous
//
#include <hip/hip_runtime.h>

#define H 2048
#define W 2048
#define KS 97     // int(2*(4*12+0.5)) = 97, odd
#define KH 48
#define KP 104    // taps zero-padded to multiple of 8 (clean unroll, no dynamic window idx)
#define TR 8      // output rows per thread, vertical pass

// ---------------------------------------------------------------------------
// wts layout: [0..103]=g0 (sigma0, zero-padded), [104..207]=g1 (sigma1, padded),
//             [208]=alpha0, [209]=alpha1
// ---------------------------------------------------------------------------
__global__ __launch_bounds__(128) void make_weights_k(const float* __restrict__ log_sigma,
                                                      const float* __restrict__ log_alpha,
                                                      float* __restrict__ wts) {
    __shared__ float e0s[KS], e1s[KS];
    __shared__ float sums[2];
    const int t = threadIdx.x;
    const float s0 = expf(log_sigma[0]);
    const float s1 = expf(log_sigma[1]);
    if (t < KS) {
        const float xx = (float)(t - KH);
        e0s[t] = expf(-(xx * xx) / (2.f * s0 * s0));
        e1s[t] = expf(-(xx * xx) / (2.f * s1 * s1));
    }
    __syncthreads();
    if (t == 0) {
        float a = 0.f, b = 0.f;
        for (int k = 0; k < KS; ++k) { a += e0s[k]; b += e1s[k]; }
        sums[0] = a; sums[1] = b;
    }
    __syncthreads();
    if (t < KP) {
        wts[t]      = (t < KS) ? e0s[t] / sums[0] : 0.f;
        wts[KP + t] = (t < KS) ? e1s[t] / sums[1] : 0.f;
    }
    if (t == 0) {
        wts[2 * KP]     = expf(log_alpha[0]);
        wts[2 * KP + 1] = expf(log_alpha[1]);
    }
}

// ---------------------------------------------------------------------------
// Kernel 1: vertical 97-tap blur of (d_rand*2-1), zero-padded SAME.
// Tap-major loop with sliding 8-row register window, 4 cols (float4) per
// thread, 8 output rows per thread. Per tap: 1×16B coalesced load,
// 1 uniform scalar tap load, 32 FMAs. No LDS, no spills.
// ---------------------------------------------------------------------------
__global__ __launch_bounds__(256) void vblur_k(const float* __restrict__ drand,
                                               const float* __restrict__ wts,
                                               float* __restrict__ tmp) {
    const int c    = blockIdx.z;
    const int col  = (blockIdx.x * 256 + threadIdx.x) * 4;
    const int i0   = blockIdx.y * TR;
    const int base = i0 - KH;
    const float* __restrict__ src = drand + (size_t)c * H * W;
    const float* __restrict__ g   = wts + c * KP;

    float4 win[8];
    float4 acc[TR];
#pragma unroll
    for (int t = 0; t < TR; ++t) acc[t] = make_float4(0.f, 0.f, 0.f, 0.f);

    // preload rows base+0 .. base+6 into win[0..6]
#pragma unroll
    for (int t = 0; t < 7; ++t) {
        const int row = base + t;
        float4 v = make_float4(0.f, 0.f, 0.f, 0.f);
        if ((unsigned)row < (unsigned)H) {
            const float4 r4 = *(const float4*)(src + (size_t)row * W + col);
            v.x = fmaf(r4.x, 2.f, -1.f);
            v.y = fmaf(r4.y, 2.f, -1.f);
            v.z = fmaf(r4.z, 2.f, -1.f);
            v.w = fmaf(r4.w, 2.f, -1.f);
        }
        win[t] = v;
    }

#pragma unroll 8
    for (int k = 0; k < KP; ++k) {
        // window must hold rows base+k .. base+k+7 in slots (k..k+7)&7
        const int row = base + k + 7;
        float4 v = make_float4(0.f, 0.f, 0.f, 0.f);
        if ((unsigned)row < (unsigned)H) {
            const float4 r4 = *(const float4*)(src + (size_t)row * W + col);
            v.x = fmaf(r4.x, 2.f, -1.f);
            v.y = fmaf(r4.y, 2.f, -1.f);
            v.z = fmaf(r4.z, 2.f, -1.f);
            v.w = fmaf(r4.w, 2.f, -1.f);
        }
        win[(k + 7) & 7] = v;
        const float gk = g[k];   // uniform -> scalar load; 0 for k>=97
#pragma unroll
        for (int t = 0; t < TR; ++t) {
            const float4 u = win[(k + t) & 7];
            acc[t].x = fmaf(gk, u.x, acc[t].x);
            acc[t].y = fmaf(gk, u.y, acc[t].y);
            acc[t].z = fmaf(gk, u.z, acc[t].z);
            acc[t].w = fmaf(gk, u.w, acc[t].w);
        }
    }

    float* __restrict__ dst = tmp + (size_t)c * H * W;
#pragma unroll
    for (int t = 0; t < TR; ++t)
        *(float4*)(dst + (size_t)(i0 + t) * W + col) = acc[t];
}

// ---------------------------------------------------------------------------
// Kernel 2: horizontal 97-tap blur of tmp -> (dy,dx), scale by alpha, build
// sample coords, bilinear-gather image(3ch)+mask(1ch).
// 2 cols per thread (lane stride 2 in LDS = free 2-way), sliding 2-reg
// window: 2 ds_read + 8 FMA per tap. Taps padded to 98 for clean unroll-2.
// Reference quirk: x-coordinate += dy (channel 0), y-coordinate += dx.
// ---------------------------------------------------------------------------
#define BC 512          // cols per block
__global__ __launch_bounds__(256) void hblur_sample_k(const float* __restrict__ tmp,
                                                      const float* __restrict__ wts,
                                                      const float* __restrict__ image,
                                                      const float* __restrict__ mask,
                                                      float* __restrict__ out) {
    const int i   = blockIdx.y;
    const int j0  = blockIdx.x * BC;
    const int tid = threadIdx.x;

    __shared__ float s0[612];   // need indices 0..608; 612 = 153 float4
    __shared__ float s1[612];

    const float* __restrict__ t0 = tmp + (size_t)i * W;
    const float* __restrict__ t1 = tmp + (size_t)H * W + (size_t)i * W;
    for (int idx = tid; idx < 153; idx += 256) {
        const int colb = j0 - KH + idx * 4;   // multiple of 4 -> 16B aligned
        float4 v0 = make_float4(0.f, 0.f, 0.f, 0.f);
        float4 v1 = v0;
        if (colb >= 0 && colb + 3 < W) {      // W mult of 4: fully in or out
            v0 = *(const float4*)(t0 + colb);
            v1 = *(const float4*)(t1 + colb);
        }
        *(float4*)(s0 + idx * 4) = v0;
        *(float4*)(s1 + idx * 4) = v1;
    }
    __syncthreads();

    const float a0 = wts[2 * KP];
    const float a1 = wts[2 * KP + 1];
    const int lb = tid * 2;

    float w0[2], w1[2];
    w0[0] = s0[lb];
    w1[0] = s1[lb];
    float dyv[2] = {0.f, 0.f}, dxv[2] = {0.f, 0.f};

#pragma unroll 2
    for (int k = 0; k < 98; ++k) {            // g[97]=0 pad -> even trip count
        w0[(k + 1) & 1] = s0[lb + k + 1];
        w1[(k + 1) & 1] = s1[lb + k + 1];
        const float g0 = wts[k];              // uniform -> scalar load
        const float g1 = wts[KP + k];
        dyv[0] = fmaf(g0, w0[k & 1], dyv[0]);
        dyv[1] = fmaf(g0, w0[(k + 1) & 1], dyv[1]);
        dxv[0] = fmaf(g1, w1[k & 1], dxv[0]);
        dxv[1] = fmaf(g1, w1[(k + 1) & 1], dxv[1]);
    }

    const float step = 2.f / 2047.f;
    float res[4][2];
#pragma unroll
    for (int c = 0; c < 2; ++c) {
        const int j = j0 + lb + c;
        const float dy = dyv[c] * a0;
        const float dx = dxv[c] * a1;
        float xn = -1.f + (float)j * step + dy;   // gx + dy  (reference quirk)
        float yn = -1.f + (float)i * step + dx;   // gy + dx
        xn = fminf(fmaxf(xn, -1.f), 1.f);
        yn = fminf(fmaxf(yn, -1.f), 1.f);

        const float x = (xn + 1.f) * 0.5f * (float)(W - 1);
        const float y = (yn + 1.f) * 0.5f * (float)(H - 1);
        const float x0f = floorf(x), y0f = floorf(y);
        const float wx = x - x0f, wy = y - y0f;

        int x0 = (int)x0f, y0 = (int)y0f;
        int x1 = x0 + 1, y1 = y0 + 1;
        x0 = min(max(x0, 0), W - 1); x1 = min(max(x1, 0), W - 1);
        y0 = min(max(y0, 0), H - 1); y1 = min(max(y1, 0), H - 1);

        const float w00 = (1.f - wx) * (1.f - wy);
        const float w10 = wx * (1.f - wy);
        const float w01 = (1.f - wx) * wy;
        const float w11 = wx * wy;

        const size_t i00 = (size_t)y0 * W + x0;
        const size_t i10 = (size_t)y0 * W + x1;
        const size_t i01 = (size_t)y1 * W + x0;
        const size_t i11 = (size_t)y1 * W + x1;

#pragma unroll
        for (int p = 0; p < 3; ++p) {
            const float* __restrict__ pl = image + (size_t)p * H * W;
            res[p][c] = pl[i00] * w00 + pl[i10] * w10 + pl[i01] * w01 + pl[i11] * w11;
        }
        res[3][c] = mask[i00] * w00 + mask[i10] * w10 + mask[i01] * w01 + mask[i11] * w11;
    }

    const size_t o = (size_t)i * W + j0 + lb;
#pragma unroll
    for (int p = 0; p < 4; ++p)
        *(float2*)(out + (size_t)p * H * W + o) = make_float2(res[p][0], res[p][1]);
}

// ---------------------------------------------------------------------------
extern "C" void kernel_launch(void* const* d_in, const int* in_sizes, int n_in,
                              void* d_out, int out_size, void* d_ws, size_t ws_size,
                              hipStream_t stream) {
    const float* image     = (const float*)d_in[0];  // (3,2048,2048)
    const float* mask      = (const float*)d_in[1];  // (1,2048,2048)
    const float* drand     = (const float*)d_in[2];  // (1,2,2048,2048)
    const float* log_sigma = (const float*)d_in[3];  // (2,)
    const float* log_alpha = (const float*)d_in[4];  // (2,)
    float* out = (float*)d_out;                      // 3*HW img ++ 1*HW mask

    float* tmp = (float*)d_ws;                       // 2*H*W floats (32 MB)
    float* wts = tmp + (size_t)2 * H * W;            // 210 floats

    make_weights_k<<<1, 128, 0, stream>>>(log_sigma, log_alpha, wts);
    vblur_k<<<dim3(W / 1024, H / TR, 2), 256, 0, stream>>>(drand, wts, tmp);
    hblur_sample_k<<<dim3(W / BC, H), 256, 0, stream>>>(tmp, wts, image, mask, out);
}